// Round 4
// baseline (178.631 us; speedup 1.0000x reference)
//
#include <hip/hip_runtime.h>
#include <math.h>

#define DIMH 256        // D
#define NB   32         // batch
#define E_TOT 43234
#define TE   128        // entities per block
#define DK   32         // d-chunk staged in LDS
#define DQ   64         // d-range per block (d-split by 4)
// reference: phase = rel / (REL_RANGE/PI); REL_RANGE/PI = 0.03125/PI
#define PHASE_DIV 0.009947183943243459f

typedef float v2f __attribute__((ext_vector_type(2)));
typedef float v4f __attribute__((ext_vector_type(4)));

// Kernel 0: out = MARGIN everywhere; dist quarters subtract via atomics.
__global__ __launch_bounds__(256) void init_kernel(float* __restrict__ out) {
    int i = blockIdx.x * 256 + threadIdx.x;
    if (i < (NB * E_TOT) / 4) {
        float4 v = make_float4(6.0f, 6.0f, 6.0f, 6.0f);
        reinterpret_cast<float4*>(out)[i] = v;
    }
}

// Kernel 1: rotate head by relation phase (fp32 sincosf).
__global__ void rot_kernel(const float* __restrict__ head,
                           const float* __restrict__ rel,
                           float* __restrict__ rot) {
    int i = blockIdx.x * blockDim.x + threadIdx.x;   // 0..8191
    int b = i >> 8;
    int d = i & 255;
    float re_h = head[b * 2 * DIMH + d];
    float im_h = head[b * 2 * DIMH + DIMH + d];
    float ph = rel[b * DIMH + d] / PHASE_DIV;
    float s, c;
    sincosf(ph, &s, &c);
    rot[b * DIMH + d]             = re_h * c - im_h * s;   // re_rot
    rot[NB * DIMH + b * DIMH + d] = re_h * s + im_h * c;   // im_rot
}

__device__ __forceinline__ v2f sqrt2(v2f s) {
    v2f r;
    r.x = __builtin_amdgcn_sqrtf(s.x);
    r.y = __builtin_amdgcn_sqrtf(s.y);
    return r;
}

// Kernel 2: block = 128-entity tile x 64-d quarter, all 32 batches.
// LDS element = float4 (re_d, re_d+1, im_d, im_d+1): one ds_read_b128 per
// row per d2-step. Row stride 17 float4 = 68 words == 4 mod 32 -> ent-read
// bank pattern identical to stride-1 b128 baseline (no extra conflicts);
// rot reads are 2-address full-wave broadcasts (~free).
// Per-thread register tile: 4 batch x 4 entity.
__global__ __launch_bounds__(256, 3) void dist_kernel(const float* __restrict__ ent,
                                                      const float* __restrict__ rot,
                                                      float* __restrict__ out) {
    __shared__ v4f s_e[TE][DK / 2 + 1];   // 128 x 17 float4 = 34.8 KB
    __shared__ v4f s_r[NB][DK / 2 + 1];   //  32 x 17 float4 =  8.7 KB

    const int tid   = threadIdx.x;
    const int etile = blockIdx.x >> 2;
    const int quart = blockIdx.x & 3;
    const int eb    = etile * TE;
    const int eg    = tid & 31;          // entity group: rows eg + 32k
    const int bg    = (tid >> 5) * 4;    // first of 4 batch rows
    const int dbase = quart * DQ;

    v2f acc[4][4];   // [batch j][entity k]
    #pragma unroll
    for (int j = 0; j < 4; ++j)
        #pragma unroll
        for (int k = 0; k < 4; ++k) { acc[j][k].x = 0.f; acc[j][k].y = 0.f; }

    for (int c = 0; c < DQ / DK; ++c) {
        const int dk = dbase + c * DK;
        // ---- stage entities: 128 rows x 8 float4-chunks of re + im
        #pragma unroll
        for (int it = 0; it < 4; ++it) {
            int q   = tid + it * 256;      // 0..1023
            int row = q >> 3;              // 0..127
            int c4  = q & 7;               // 0..7 -> d = dk + 4*c4
            int er  = eb + row;
            if (er >= E_TOT) er = E_TOT - 1;   // clamp tail (stores guarded later)
            const float* base = &ent[(size_t)er * (2 * DIMH)];
            float4 vre = *reinterpret_cast<const float4*>(base + dk + 4 * c4);
            float4 vim = *reinterpret_cast<const float4*>(base + DIMH + dk + 4 * c4);
            v4f lo, hi;
            lo.x = vre.x; lo.y = vre.y; lo.z = vim.x; lo.w = vim.y;
            hi.x = vre.z; hi.y = vre.w; hi.z = vim.z; hi.w = vim.w;
            s_e[row][2 * c4]     = lo;
            s_e[row][2 * c4 + 1] = hi;
        }
        // ---- stage rot: 32 rows x 8 float4-chunks
        {
            int row = tid >> 3;            // 0..31
            int c4  = tid & 7;             // 0..7
            float4 vrr = *reinterpret_cast<const float4*>(&rot[row * DIMH + dk + 4 * c4]);
            float4 vri = *reinterpret_cast<const float4*>(&rot[NB * DIMH + row * DIMH + dk + 4 * c4]);
            v4f lo, hi;
            lo.x = vrr.x; lo.y = vrr.y; lo.z = vri.x; lo.w = vri.y;
            hi.x = vrr.z; hi.y = vrr.w; hi.z = vri.z; hi.w = vri.w;
            s_r[row][2 * c4]     = lo;
            s_r[row][2 * c4 + 1] = hi;
        }
        __syncthreads();

        #pragma unroll 4
        for (int p = 0; p < DK / 2; ++p) {
            v4f r4[4], e4[4];
            #pragma unroll
            for (int j = 0; j < 4; ++j) r4[j] = s_r[bg + j][p];
            #pragma unroll
            for (int k = 0; k < 4; ++k) e4[k] = s_e[eg + 32 * k][p];
            #pragma unroll
            for (int j = 0; j < 4; ++j)
                #pragma unroll
                for (int k = 0; k < 4; ++k) {
                    v2f a = r4[j].xy - e4[k].xy;   // re diff (packed)
                    v2f b = r4[j].zw - e4[k].zw;   // im diff (packed)
                    v2f s = a * a + b * b;         // v_pk_mul + v_pk_fma
                    acc[j][k] += sqrt2(s);         // v_pk_add
                }
        }
        __syncthreads();
    }

    #pragma unroll
    for (int k = 0; k < 4; ++k) {
        int e = eb + eg + 32 * k;
        if (e < E_TOT) {
            #pragma unroll
            for (int j = 0; j < 4; ++j)
                atomicAdd(&out[(size_t)(bg + j) * E_TOT + e],
                          -(acc[j][k].x + acc[j][k].y));
        }
    }
}

extern "C" void kernel_launch(void* const* d_in, const int* in_sizes, int n_in,
                              void* d_out, int out_size, void* d_ws, size_t ws_size,
                              hipStream_t stream) {
    const float* head = (const float*)d_in[0];   // (32, 512)
    const float* rel  = (const float*)d_in[1];   // (32, 256)
    const float* ent  = (const float*)d_in[2];   // (43234, 512)
    float* rot = (float*)d_ws;                   // 2 * 32 * 256 floats = 64 KB

    int init_blocks = ((NB * E_TOT) / 4 + 255) / 256;   // 1352
    init_kernel<<<init_blocks, 256, 0, stream>>>((float*)d_out);
    rot_kernel<<<(NB * DIMH) / 256, 256, 0, stream>>>(head, rel, rot);

    int etiles = (E_TOT + TE - 1) / TE;          // 338
    dist_kernel<<<etiles * 4, 256, 0, stream>>>(ent, rot, (float*)d_out);
}